// Round 2
// baseline (444.377 us; speedup 1.0000x reference)
//
#include <hip/hip_runtime.h>

#define NT 150      // trees
#define NPT 341     // nodes per tree
#define LEAF0 85    // first leaf local index
#define NL (NT*256) // 38400 leaves
#define NN (NT*NPT) // 51150 nodes
#define VOCAB 10000

typedef __attribute__((ext_vector_type(8))) short short8;
typedef __attribute__((ext_vector_type(4))) float floatx4;

__device__ __forceinline__ float sigf(float x){
  return __builtin_amdgcn_rcpf(1.0f + __expf(-x));
}
__device__ __forceinline__ float tanh_fast(float x){
  float e = __expf(2.0f*x);
  return 1.0f - 2.0f*__builtin_amdgcn_rcpf(e + 1.0f);
}
__device__ __forceinline__ float bf2f(ushort u){ union{unsigned i; float f;} v; v.i = ((unsigned)u)<<16; return v.f; }
__device__ __forceinline__ ushort f2bf(float x){ union{float f; unsigned i;} v; v.f = x; return (ushort)((v.i + 0x7fff + ((v.i>>16)&1))>>16); }

// ---------- prep: weight transpose+convert AND embedding-table convert ------
__global__ __launch_bounds__(256) void prep_k(
    const float* __restrict__ e1, const float* __restrict__ e2,
    ushort* __restrict__ E1, ushort* __restrict__ E2,
    const float* __restrict__ W1, const float* __restrict__ U1, const float* __restrict__ F1,
    const float* __restrict__ W2, const float* __restrict__ U2, const float* __restrict__ F2,
    ushort* Wt1, ushort* Ut1, ushort* Ft1, ushort* Wt2, ushort* Ut2, ushort* Ft2){
  __shared__ float T[32][33];
  int bid = blockIdx.x;
  if (bid < 5000){
    const float* s = (bid >= 2500) ? e2 : e1;
    ushort* d = (bid >= 2500) ? E2 : E1;
    size_t i = ((size_t)(bid % 2500)*256 + threadIdx.x)*4;
    float4 v = *(const float4*)&s[i];
    d[i+0]=f2bf(v.x); d[i+1]=f2bf(v.y); d[i+2]=f2bf(v.z); d[i+3]=f2bf(v.w);
    return;
  }
  int w = bid - 5000;            // [0, 1152)
  int z = w / 192, rem = w % 192;
  int bx = rem % 24, by = rem / 24;
  const float* src; ushort* dst; int N;
  switch (z){
    case 0: src=W1; dst=Wt1; N=768; break;
    case 1: src=U1; dst=Ut1; N=768; break;
    case 2: src=F1; dst=Ft1; N=256; break;
    case 3: src=W2; dst=Wt2; N=768; break;
    case 4: src=U2; dst=Ut2; N=768; break;
    default: src=F2; dst=Ft2; N=256; break;
  }
  int n0 = bx*32; if (n0 >= N) return;
  int k0 = by*32;
  int nl = threadIdx.x & 31, kb = threadIdx.x >> 5;
  #pragma unroll
  for (int i=0;i<4;i++){ int kk = kb*4+i; T[kk][nl] = src[(size_t)(k0+kk)*N + n0 + nl]; }
  __syncthreads();
  #pragma unroll
  for (int i=0;i<4;i++){ int nn = kb*4+i; dst[(size_t)(n0+nn)*256 + k0 + nl] = f2bf(T[nl][nn]); }
}

// ---------- leaf GEMM with fused embed; LDS-staged coalesced h/c stores -----
__global__ __launch_bounds__(1024) void leaf_gemm(
    const int* __restrict__ f1, const int* __restrict__ f2,
    const ushort* __restrict__ E1, const ushort* __restrict__ E2,
    const ushort* __restrict__ Wt1, const float* __restrict__ b1,
    const ushort* __restrict__ Wt2, const float* __restrict__ b2,
    ushort* __restrict__ h1, ushort* __restrict__ c1,
    ushort* __restrict__ h2, ushort* __restrict__ c2){
  __shared__ __attribute__((aligned(16))) ushort As[8][64*40];
  int br = blockIdx.y;
  const int* feat = br ? f2 : f1;
  const ushort* E = br ? E2 : E1;
  const ushort* Wt = br ? Wt2 : Wt1;
  const float* biou = br ? b2 : b1;
  ushort* h = br ? h2 : h1;
  ushort* c = br ? c2 : c1;
  int tid = threadIdx.x;
  int lane = tid & 63, wav = tid >> 6, quad = lane >> 4, l15 = lane & 15;
  int rowbase = blockIdx.x*64;

  { // fused embed: mean of 8 subtoken rows -> bf16 -> LDS A-tile (one barrier)
    int row = tid >> 4, seg = tid & 15;
    int leaf = rowbase + row;
    int tree = leaf >> 8;
    size_t node = (size_t)tree*NPT + LEAF0 + (leaf & 255);
    const int* f = feat + node*8;
    int4 fA = *(const int4*)f;
    int4 fB = *(const int4*)(f+4);
    int idx[8] = {fA.x, fA.y, fA.z, fA.w, fB.x, fB.y, fB.z, fB.w};
    float s[16];
    #pragma unroll
    for (int q=0;q<16;q++) s[q]=0.f;
    #pragma unroll
    for (int half=0; half<2; half++){
      short8 va[4], vb[4];
      #pragma unroll
      for (int j=0;j<4;j++){
        const ushort* rowp = E + (size_t)idx[half*4+j]*256 + seg*16;
        va[j] = *(const short8*)rowp;
        vb[j] = *(const short8*)(rowp+8);
      }
      #pragma unroll
      for (int j=0;j<4;j++){
        #pragma unroll
        for (int q=0;q<8;q++){ s[q]+=bf2f((ushort)va[j][q]); s[8+q]+=bf2f((ushort)vb[j][q]); }
      }
    }
    short8 o1, o2;
    #pragma unroll
    for (int q=0;q<8;q++){ o1[q]=(short)f2bf(s[q]*0.125f); o2[q]=(short)f2bf(s[8+q]*0.125f); }
    int cch = seg >> 1, off = (seg & 1)*16;
    *(short8*)&As[cch][row*40 + off]     = o1;
    *(short8*)&As[cch][row*40 + off + 8] = o2;
  }
  __syncthreads();

  floatx4 acc[3][4];
  #pragma unroll
  for (int g=0;g<3;g++)
    #pragma unroll
    for (int r=0;r<4;r++) acc[g][r] = (floatx4){0.f,0.f,0.f,0.f};

  const ushort* bp0 = Wt + (size_t)(0*256 + wav*16 + l15)*256 + quad*8;
  const ushort* bp1 = Wt + (size_t)(1*256 + wav*16 + l15)*256 + quad*8;
  const ushort* bp2 = Wt + (size_t)(2*256 + wav*16 + l15)*256 + quad*8;

  #pragma unroll
  for (int cch=0; cch<8; cch++){
    short8 b0 = *(const short8*)(bp0 + cch*32);
    short8 b1 = *(const short8*)(bp1 + cch*32);
    short8 b2 = *(const short8*)(bp2 + cch*32);
    #pragma unroll
    for (int r=0;r<4;r++){
      short8 a = *(const short8*)&As[cch][(16*r + l15)*40 + quad*8];
      acc[0][r] = __builtin_amdgcn_mfma_f32_16x16x32_bf16(a, b0, acc[0][r], 0,0,0);
      acc[1][r] = __builtin_amdgcn_mfma_f32_16x16x32_bf16(a, b1, acc[1][r], 0,0,0);
      acc[2][r] = __builtin_amdgcn_mfma_f32_16x16x32_bf16(a, b2, acc[2][r], 0,0,0);
    }
  }
  int hc = wav*16 + l15;
  float bi = biou[hc], bo = biou[256+hc], bu = biou[512+hc];
  ushort hv[16], cv[16];
  #pragma unroll
  for (int r=0;r<4;r++){
    #pragma unroll
    for (int reg=0;reg<4;reg++){
      float iv = acc[0][r][reg] + bi;
      float ov = acc[1][r][reg] + bo;
      float uv = acc[2][r][reg] + bu;
      float cc = sigf(iv)*tanh_fast(uv);
      float hh = sigf(ov)*tanh_fast(cc);
      hv[4*r+reg] = f2bf(hh);
      cv[4*r+reg] = f2bf(cc);
    }
  }
  // ---- staged coalesced stores (kills partial-line RMW fetches) ----
  ushort* Hs = &As[0][0];   // reuse as [64][256], chunk-XOR swizzled
  __syncthreads();          // all MFMA A-reads done
  #pragma unroll
  for (int r=0;r<4;r++){
    #pragma unroll
    for (int reg=0;reg<4;reg++)
      Hs[(size_t)(16*r + quad*4 + reg)*256 + (((wav ^ quad)<<4) + l15)] = hv[4*r+reg];
  }
  __syncthreads();
  {
    int row = tid>>4, c16 = tid & 15;
    int leaf = rowbase + row, tree = leaf >> 8;
    size_t node = (size_t)tree*NPT + LEAF0 + (leaf & 255);
    const ushort* sp = &Hs[(size_t)row*256 + ((c16 ^ ((row>>2)&3))<<4)];
    ushort* dp = h + node*256 + c16*16;
    *(short8*)dp = *(const short8*)sp;
    *(short8*)(dp+8) = *(const short8*)(sp+8);
  }
  __syncthreads();
  #pragma unroll
  for (int r=0;r<4;r++){
    #pragma unroll
    for (int reg=0;reg<4;reg++)
      Hs[(size_t)(16*r + quad*4 + reg)*256 + (((wav ^ quad)<<4) + l15)] = cv[4*r+reg];
  }
  __syncthreads();
  {
    int row = tid>>4, c16 = tid & 15;
    int leaf = rowbase + row, tree = leaf >> 8;
    size_t node = (size_t)tree*NPT + LEAF0 + (leaf & 255);
    const ushort* sp = &Hs[(size_t)row*256 + ((c16 ^ ((row>>2)&3))<<4)];
    ushort* dp = c + node*256 + c16*16;
    *(short8*)dp = *(const short8*)sp;
    *(short8*)(dp+8) = *(const short8*)(sp+8);
  }
}

// ---------- internal level: per-child MFMA; LDS-staged coalesced stores -----
__global__ __launch_bounds__(256) void level_k(
    const ushort* __restrict__ Ut1, const ushort* __restrict__ Ft1,
    const float* __restrict__ Ufb1, const float* __restrict__ bi1,
    const ushort* __restrict__ Ut2, const ushort* __restrict__ Ft2,
    const float* __restrict__ Ufb2, const float* __restrict__ bi2,
    ushort* __restrict__ h1, ushort* __restrict__ c1,
    ushort* __restrict__ h2, ushort* __restrict__ c2,
    int M, int shift, int base){
  __shared__ __attribute__((aligned(16))) ushort Ch[8][64*40];
  int br = blockIdx.z;
  const ushort* Ut = br ? Ut2 : Ut1;
  const ushort* Ft = br ? Ft2 : Ft1;
  const float* Ufb = br ? Ufb2 : Ufb1;
  const float* biou = br ? bi2 : bi1;
  ushort* h = br ? h2 : h1;
  ushort* c = br ? c2 : c1;
  int tid = threadIdx.x;
  int lane = tid & 63, wav = tid >> 6, quad = lane >> 4, l15 = lane & 15;
  int m0 = blockIdx.x*16, cb = blockIdx.y;
  int mask = (1<<shift)-1;

  { // stage 64 children rows x 256 k (one barrier)
    int cl = tid >> 2, q4 = tid & 3;
    int sm = m0 + (cl >> 2); if (sm > M-1) sm = M-1;
    int stree = sm >> shift, sloc = base + (sm & mask);
    const ushort* sgp = h + ((size_t)stree*NPT + 4*sloc + 1 + (cl & 3))*256 + q4*8;
    #pragma unroll
    for (int cc=0;cc<8;cc++)
      *(short8*)&Ch[cc][cl*40 + q4*8] = *(const short8*)(sgp + cc*32);
  }
  __syncthreads();

  int col = cb*64 + wav*16 + l15;
  const ushort* bfp = Ft + (size_t)col*256 + quad*8;
  const ushort* bp0 = Ut + (size_t)(0*256 + col)*256 + quad*8;
  const ushort* bp1 = Ut + (size_t)(256 + col)*256 + quad*8;
  const ushort* bp2 = Ut + (size_t)(512 + col)*256 + quad*8;

  floatx4 af[4], ai[4], ao[4], au[4];
  #pragma unroll
  for (int r=0;r<4;r++){
    af[r] = (floatx4){0.f,0.f,0.f,0.f}; ai[r] = (floatx4){0.f,0.f,0.f,0.f};
    ao[r] = (floatx4){0.f,0.f,0.f,0.f}; au[r] = (floatx4){0.f,0.f,0.f,0.f};
  }

  #pragma unroll
  for (int cc=0; cc<8; cc++){
    short8 Bf = *(const short8*)(bfp + cc*32);
    short8 Bi = *(const short8*)(bp0 + cc*32);
    short8 Bo = *(const short8*)(bp1 + cc*32);
    short8 Bu = *(const short8*)(bp2 + cc*32);
    #pragma unroll
    for (int r=0;r<4;r++){
      short8 a = *(const short8*)&Ch[cc][(16*r + l15)*40 + quad*8];
      af[r] = __builtin_amdgcn_mfma_f32_16x16x32_bf16(a, Bf, af[r], 0,0,0);
      ai[r] = __builtin_amdgcn_mfma_f32_16x16x32_bf16(a, Bi, ai[r], 0,0,0);
      ao[r] = __builtin_amdgcn_mfma_f32_16x16x32_bf16(a, Bo, ao[r], 0,0,0);
      au[r] = __builtin_amdgcn_mfma_f32_16x16x32_bf16(a, Bu, au[r], 0,0,0);
    }
  }

  float ufb = Ufb[col];
  float bI = biou[col], bO = biou[256+col], bU = biou[512+col];
  ushort hv[4], cvv[4];
  #pragma unroll
  for (int r=0;r<4;r++){
    int m = m0 + 4*r + quad;
    int mm = m < M ? m : M-1;
    int tree = mm >> shift, loc = base + (mm & mask);
    size_t ch0 = ((size_t)tree*NPT + 4*loc + 1)*256 + col;
    float cs = 0.f;
    #pragma unroll
    for (int reg=0;reg<4;reg++)
      cs += sigf(af[r][reg] + ufb) * bf2f(c[ch0 + (size_t)reg*256]);
    float iv = ai[r][0]+ai[r][1]+ai[r][2]+ai[r][3] + bI;
    float ov = ao[r][0]+ao[r][1]+ao[r][2]+ao[r][3] + bO;
    float uv = au[r][0]+au[r][1]+au[r][2]+au[r][3] + bU;
    float cn = sigf(iv)*tanh_fast(uv) + cs;
    float hn = sigf(ov)*tanh_fast(cn);
    hv[r] = f2bf(hn); cvv[r] = f2bf(cn);
  }
  // ---- staged coalesced stores: 16 nodes x 64 cols, 128 B/node ----
  __syncthreads();          // Ch MFMA reads done
  ushort* Lh = &Ch[0][0];   // [16][64] chunk-XOR swizzled
  ushort* Lc = Lh + 1024;
  #pragma unroll
  for (int r=0;r<4;r++){
    int li = (4*r + quad)*64 + (((wav ^ quad)<<4) + l15);
    Lh[li] = hv[r]; Lc[li] = cvv[r];
  }
  __syncthreads();
  {
    int nloc = tid >> 4, c4 = tid & 15;
    int m = m0 + nloc;
    if (m < M){
      int tree = m >> shift, loc = base + (m & mask);
      int si = nloc*64 + ((((c4>>2) ^ (nloc&3))<<4) + (c4&3)*4);
      ushort4 hq = *(const ushort4*)&Lh[si];
      ushort4 cq = *(const ushort4*)&Lc[si];
      size_t off = ((size_t)tree*NPT + loc)*256 + cb*64 + c4*4;
      *(ushort4*)&h[off] = hq;
      *(ushort4*)&c[off] = cq;
    }
  }
}

// ---------- readout partials: vectorized (ushort4/lane, 4 row-groups) -------
__global__ __launch_bounds__(256) void readout_k(
    const ushort* __restrict__ h1, const ushort* __restrict__ h2,
    float* __restrict__ mp1, float* __restrict__ mp2){
  __shared__ float red[4][256];
  int br = blockIdx.z, part = blockIdx.y, tree = blockIdx.x;
  const ushort* h = br ? h2 : h1;
  float* mp = br ? mp2 : mp1;
  int t = threadIdx.x;
  int lane = t & 63, rg = t >> 6;
  int start = part*85;
  int cnt = (part==3) ? 86 : 85;
  const ushort* base = h + ((size_t)tree*NPT + start)*256 + lane*4;
  float s0=0.f,s1=0.f,s2=0.f,s3=0.f;
  for (int i=rg; i<cnt; i+=4){
    ushort4 v = *(const ushort4*)(base + (size_t)i*256);
    s0 += bf2f(v.x); s1 += bf2f(v.y); s2 += bf2f(v.z); s3 += bf2f(v.w);
  }
  *(float4*)&red[rg][lane*4] = make_float4(s0,s1,s2,s3);
  __syncthreads();
  float tot = red[0][t]+red[1][t]+red[2][t]+red[3][t];
  mp[((size_t)tree*4 + part)*256 + t] = tot;
}

// ---------- final: mean->relu->concat@Wf->leaky_relu->softmax ---------------
__global__ __launch_bounds__(64) void final_k(const float* __restrict__ mp1,
    const float* __restrict__ mp2, const float* __restrict__ Wf,
    const float* __restrict__ bf, float* __restrict__ out){
  int tree = blockIdx.x; int t = threadIdx.x;
  float p0=0.f, p1=0.f;
  for (int k=t;k<512;k+=64){
    const float* mp = (k<256) ? mp1 : mp2;
    int kk = k & 255;
    size_t b0 = ((size_t)tree*4)*256 + kk;
    float s = mp[b0] + mp[b0+256] + mp[b0+512] + mp[b0+768];
    float x = fmaxf(s*(1.0f/341.0f), 0.f);
    p0 += x*Wf[k*2+0]; p1 += x*Wf[k*2+1];
  }
  #pragma unroll
  for (int off=32; off>0; off>>=1){
    p0 += __shfl_down(p0, off);
    p1 += __shfl_down(p1, off);
  }
  if (t==0){
    float l0 = p0+bf[0], l1 = p1+bf[1];
    l0 = (l0>0.f)?l0:0.01f*l0;
    l1 = (l1>0.f)?l1:0.01f*l1;
    float mx = fmaxf(l0,l1);
    float e0 = __expf(l0-mx), e1 = __expf(l1-mx);
    float inv = 1.0f/(e0+e1);
    out[tree*2+0] = e0*inv; out[tree*2+1] = e1*inv;
  }
}

extern "C" void kernel_launch(void* const* d_in, const int* in_sizes, int n_in,
                              void* d_out, int out_size, void* d_ws, size_t ws_size,
                              hipStream_t stream) {
  const int*   feat1 = (const int*)  d_in[0];
  const int*   feat2 = (const int*)  d_in[1];
  const float* emb1  = (const float*)d_in[2];
  const float* emb2  = (const float*)d_in[3];
  const float* Wiou1 = (const float*)d_in[4];
  const float* Wiou2 = (const float*)d_in[5];
  const float* Uiou1 = (const float*)d_in[6];
  const float* Uiou2 = (const float*)d_in[7];
  const float* UfW1  = (const float*)d_in[8];
  const float* Ufb1  = (const float*)d_in[9];
  const float* UfW2  = (const float*)d_in[10];
  const float* Ufb2  = (const float*)d_in[11];
  const float* biou1 = (const float*)d_in[12];
  const float* biou2 = (const float*)d_in[13];
  const float* Wf    = (const float*)d_in[14];
  const float* bfv   = (const float*)d_in[15];
  float* out = (float*)d_out;

  char* ws = (char*)d_ws;
  ushort* h1  = (ushort*)ws;  ws += (size_t)NN*256*2;   // 26.2 MB
  ushort* h2  = (ushort*)ws;  ws += (size_t)NN*256*2;
  ushort* c1  = (ushort*)ws;  ws += (size_t)NN*256*2;
  ushort* c2  = (ushort*)ws;  ws += (size_t)NN*256*2;
  ushort* E1  = (ushort*)ws;  ws += (size_t)VOCAB*256*2; // 5.12 MB
  ushort* E2  = (ushort*)ws;  ws += (size_t)VOCAB*256*2;
  ushort* Wt1 = (ushort*)ws;  ws += 768*256*2;
  ushort* Ut1 = (ushort*)ws;  ws += 768*256*2;
  ushort* Ft1 = (ushort*)ws;  ws += 256*256*2;
  ushort* Wt2 = (ushort*)ws;  ws += 768*256*2;
  ushort* Ut2 = (ushort*)ws;  ws += 768*256*2;
  ushort* Ft2 = (ushort*)ws;  ws += 256*256*2;
  float*  mp1 = (float*)ws;   ws += (size_t)NT*4*256*4;
  float*  mp2 = (float*)ws;   ws += (size_t)NT*4*256*4;

  prep_k<<<dim3(6152), 256, 0, stream>>>(emb1, emb2, E1, E2,
                                         Wiou1, Uiou1, UfW1, Wiou2, Uiou2, UfW2,
                                         Wt1, Ut1, Ft1, Wt2, Ut2, Ft2);
  leaf_gemm<<<dim3(NL/64, 2), 1024, 0, stream>>>(feat1, feat2, E1, E2,
                                                 Wt1, biou1, Wt2, biou2,
                                                 h1, c1, h2, c2);

  const int lvlM[4]     = {9600, 2400, 600, 150};
  const int lvlShift[4] = {6, 4, 2, 0};
  const int lvlBase[4]  = {21, 5, 1, 0};
  for (int l=0;l<4;l++){
    int gx = (lvlM[l] + 15)/16;
    level_k<<<dim3(gx, 4, 2), 256, 0, stream>>>(Ut1, Ft1, Ufb1, biou1,
                                                Ut2, Ft2, Ufb2, biou2,
                                                h1, c1, h2, c2,
                                                lvlM[l], lvlShift[l], lvlBase[l]);
  }
  readout_k<<<dim3(NT, 4, 2), 256, 0, stream>>>(h1, h2, mp1, mp2);
  final_k<<<NT, 64, 0, stream>>>(mp1, mp2, Wf, bfv, out);
}

// Round 3
// 403.483 us; speedup vs baseline: 1.1014x; 1.1014x over previous
//
#include <hip/hip_runtime.h>

#define NT 150      // trees
#define NPT 341     // nodes per tree
#define LEAF0 85    // first leaf local index
#define NL (NT*256) // 38400 leaves
#define NN (NT*NPT) // 51150 nodes
#define VOCAB 10000

typedef __attribute__((ext_vector_type(8))) short short8;
typedef __attribute__((ext_vector_type(4))) float floatx4;

__device__ __forceinline__ float sigf(float x){
  return __builtin_amdgcn_rcpf(1.0f + __expf(-x));
}
__device__ __forceinline__ float tanh_fast(float x){
  float e = __expf(2.0f*x);
  return 1.0f - 2.0f*__builtin_amdgcn_rcpf(e + 1.0f);
}
__device__ __forceinline__ float bf2f(ushort u){ union{unsigned i; float f;} v; v.i = ((unsigned)u)<<16; return v.f; }
__device__ __forceinline__ ushort f2bf(float x){ union{float f; unsigned i;} v; v.f = x; return (ushort)((v.i + 0x7fff + ((v.i>>16)&1))>>16); }

// ---------- prep: weight transpose+convert AND embedding-table convert ------
__global__ __launch_bounds__(256) void prep_k(
    const float* __restrict__ e1, const float* __restrict__ e2,
    ushort* __restrict__ E1, ushort* __restrict__ E2,
    const float* __restrict__ W1, const float* __restrict__ U1, const float* __restrict__ F1,
    const float* __restrict__ W2, const float* __restrict__ U2, const float* __restrict__ F2,
    ushort* Wt1, ushort* Ut1, ushort* Ft1, ushort* Wt2, ushort* Ut2, ushort* Ft2){
  __shared__ float T[32][33];
  int bid = blockIdx.x;
  if (bid < 5000){
    const float* s = (bid >= 2500) ? e2 : e1;
    ushort* d = (bid >= 2500) ? E2 : E1;
    size_t i = ((size_t)(bid % 2500)*256 + threadIdx.x)*4;
    float4 v = *(const float4*)&s[i];
    d[i+0]=f2bf(v.x); d[i+1]=f2bf(v.y); d[i+2]=f2bf(v.z); d[i+3]=f2bf(v.w);
    return;
  }
  int w = bid - 5000;            // [0, 1152)
  int z = w / 192, rem = w % 192;
  int bx = rem % 24, by = rem / 24;
  const float* src; ushort* dst; int N;
  switch (z){
    case 0: src=W1; dst=Wt1; N=768; break;
    case 1: src=U1; dst=Ut1; N=768; break;
    case 2: src=F1; dst=Ft1; N=256; break;
    case 3: src=W2; dst=Wt2; N=768; break;
    case 4: src=U2; dst=Ut2; N=768; break;
    default: src=F2; dst=Ft2; N=256; break;
  }
  int n0 = bx*32; if (n0 >= N) return;
  int k0 = by*32;
  int nl = threadIdx.x & 31, kb = threadIdx.x >> 5;
  #pragma unroll
  for (int i=0;i<4;i++){ int kk = kb*4+i; T[kk][nl] = src[(size_t)(k0+kk)*N + n0 + nl]; }
  __syncthreads();
  #pragma unroll
  for (int i=0;i<4;i++){ int nn = kb*4+i; dst[(size_t)(n0+nn)*256 + k0 + nl] = f2bf(T[nl][nn]); }
}

// ---------- leaf GEMM, 512 threads / 32 leaves: fused embed + W_iou ---------
// Each of 8 waves covers 2 col-16-groups x 3 gates; 96 MFMA/wave.
__global__ __launch_bounds__(512) void leaf_gemm(
    const int* __restrict__ f1, const int* __restrict__ f2,
    const ushort* __restrict__ E1, const ushort* __restrict__ E2,
    const ushort* __restrict__ Wt1, const float* __restrict__ b1,
    const ushort* __restrict__ Wt2, const float* __restrict__ b2,
    ushort* __restrict__ h1, ushort* __restrict__ c1,
    ushort* __restrict__ h2, ushort* __restrict__ c2){
  __shared__ __attribute__((aligned(16))) ushort As[8][32*40];  // 20 KB
  int br = blockIdx.y;
  const int* feat = br ? f2 : f1;
  const ushort* E = br ? E2 : E1;
  const ushort* Wt = br ? Wt2 : Wt1;
  const float* biou = br ? b2 : b1;
  ushort* h = br ? h2 : h1;
  ushort* c = br ? c2 : c1;
  int tid = threadIdx.x;
  int lane = tid & 63, wav = tid >> 6, quad = lane >> 4, l15 = lane & 15;
  int rowbase = blockIdx.x*32;

  { // fused embed: mean of 8 subtoken rows -> bf16 -> LDS A-tile (one barrier)
    int row = tid >> 4, seg = tid & 15;      // 32 rows x 16 segs
    int leaf = rowbase + row;
    int tree = leaf >> 8;
    size_t node = (size_t)tree*NPT + LEAF0 + (leaf & 255);
    const int* f = feat + node*8;
    int4 fA = *(const int4*)f;
    int4 fB = *(const int4*)(f+4);
    int idx[8] = {fA.x, fA.y, fA.z, fA.w, fB.x, fB.y, fB.z, fB.w};
    float s[16];
    #pragma unroll
    for (int q=0;q<16;q++) s[q]=0.f;
    #pragma unroll
    for (int half=0; half<2; half++){
      short8 va[4], vb[4];
      #pragma unroll
      for (int j=0;j<4;j++){
        const ushort* rowp = E + (size_t)idx[half*4+j]*256 + seg*16;
        va[j] = *(const short8*)rowp;
        vb[j] = *(const short8*)(rowp+8);
      }
      #pragma unroll
      for (int j=0;j<4;j++){
        #pragma unroll
        for (int q=0;q<8;q++){ s[q]+=bf2f((ushort)va[j][q]); s[8+q]+=bf2f((ushort)vb[j][q]); }
      }
    }
    short8 o1, o2;
    #pragma unroll
    for (int q=0;q<8;q++){ o1[q]=(short)f2bf(s[q]*0.125f); o2[q]=(short)f2bf(s[8+q]*0.125f); }
    int cch = seg >> 1, off = (seg & 1)*16;
    *(short8*)&As[cch][row*40 + off]     = o1;
    *(short8*)&As[cch][row*40 + off + 8] = o2;
  }
  __syncthreads();

  floatx4 acc[3][2][2];  // [gate][colgroup][rowtile]
  #pragma unroll
  for (int g=0;g<3;g++)
    #pragma unroll
    for (int cg=0;cg<2;cg++)
      #pragma unroll
      for (int r=0;r<2;r++) acc[g][cg][r] = (floatx4){0.f,0.f,0.f,0.f};

  const ushort* bp[3][2];
  #pragma unroll
  for (int g=0;g<3;g++)
    #pragma unroll
    for (int cg=0;cg<2;cg++)
      bp[g][cg] = Wt + (size_t)(g*256 + cg*128 + wav*16 + l15)*256 + quad*8;

  #pragma unroll
  for (int cch=0; cch<8; cch++){
    short8 B[3][2];
    #pragma unroll
    for (int g=0;g<3;g++)
      #pragma unroll
      for (int cg=0;cg<2;cg++) B[g][cg] = *(const short8*)(bp[g][cg] + cch*32);
    #pragma unroll
    for (int r=0;r<2;r++){
      short8 a = *(const short8*)&As[cch][(16*r + l15)*40 + quad*8];
      #pragma unroll
      for (int g=0;g<3;g++)
        #pragma unroll
        for (int cg=0;cg<2;cg++)
          acc[g][cg][r] = __builtin_amdgcn_mfma_f32_16x16x32_bf16(a, B[g][cg], acc[g][cg][r], 0,0,0);
    }
  }
  #pragma unroll
  for (int cg=0;cg<2;cg++){
    int hc = cg*128 + wav*16 + l15;
    float bi = biou[hc], bo = biou[256+hc], bu = biou[512+hc];
    #pragma unroll
    for (int r=0;r<2;r++){
      #pragma unroll
      for (int reg=0;reg<4;reg++){
        int leaf = rowbase + 16*r + quad*4 + reg;
        int tree = leaf >> 8;
        size_t node = (size_t)tree*NPT + LEAF0 + (leaf & 255);
        float iv = acc[0][cg][r][reg] + bi;
        float ov = acc[1][cg][r][reg] + bo;
        float uv = acc[2][cg][r][reg] + bu;
        float cc = sigf(iv)*tanh_fast(uv);
        float hh = sigf(ov)*tanh_fast(cc);
        h[node*256 + hc] = f2bf(hh);
        c[node*256 + hc] = f2bf(cc);
      }
    }
  }
}

// ---------- internal level, 512 threads: 16 nodes x 128 cols per block ------
// Children tile (64 rows x 256 k) staged ONCE, consumed by 8 waves.
__global__ __launch_bounds__(512) void level_k(
    const ushort* __restrict__ Ut1, const ushort* __restrict__ Ft1,
    const float* __restrict__ Ufb1, const float* __restrict__ bi1,
    const ushort* __restrict__ Ut2, const ushort* __restrict__ Ft2,
    const float* __restrict__ Ufb2, const float* __restrict__ bi2,
    ushort* __restrict__ h1, ushort* __restrict__ c1,
    ushort* __restrict__ h2, ushort* __restrict__ c2,
    int M, int shift, int base){
  __shared__ __attribute__((aligned(16))) ushort Ch[8][64*40];  // 40 KB
  int br = blockIdx.z;
  const ushort* Ut = br ? Ut2 : Ut1;
  const ushort* Ft = br ? Ft2 : Ft1;
  const float* Ufb = br ? Ufb2 : Ufb1;
  const float* biou = br ? bi2 : bi1;
  ushort* h = br ? h2 : h1;
  ushort* c = br ? c2 : c1;
  int tid = threadIdx.x;
  int lane = tid & 63, wav = tid >> 6, quad = lane >> 4, l15 = lane & 15;
  int m0 = blockIdx.x*16;
  int mask = (1<<shift)-1;

  { // stage 64 children rows x 256 k (8 threads/row, 64 B each)
    int cl = tid >> 3, s8 = tid & 7;
    int sm = m0 + (cl >> 2); if (sm > M-1) sm = M-1;
    int stree = sm >> shift, sloc = base + (sm & mask);
    const ushort* sgp = h + ((size_t)stree*NPT + 4*sloc + 1 + (cl & 3))*256 + s8*32;
    short8 v0 = *(const short8*)(sgp);
    short8 v1 = *(const short8*)(sgp+8);
    short8 v2 = *(const short8*)(sgp+16);
    short8 v3 = *(const short8*)(sgp+24);
    *(short8*)&Ch[s8][cl*40 + 0]  = v0;
    *(short8*)&Ch[s8][cl*40 + 8]  = v1;
    *(short8*)&Ch[s8][cl*40 + 16] = v2;
    *(short8*)&Ch[s8][cl*40 + 24] = v3;
  }
  __syncthreads();

  int col = blockIdx.y*128 + wav*16 + l15;
  const ushort* bfp = Ft + (size_t)col*256 + quad*8;
  const ushort* bp0 = Ut + (size_t)(0*256 + col)*256 + quad*8;
  const ushort* bp1 = Ut + (size_t)(256 + col)*256 + quad*8;
  const ushort* bp2 = Ut + (size_t)(512 + col)*256 + quad*8;

  floatx4 af[4], ai[4], ao[4], au[4];
  #pragma unroll
  for (int r=0;r<4;r++){
    af[r] = (floatx4){0.f,0.f,0.f,0.f}; ai[r] = (floatx4){0.f,0.f,0.f,0.f};
    ao[r] = (floatx4){0.f,0.f,0.f,0.f}; au[r] = (floatx4){0.f,0.f,0.f,0.f};
  }

  #pragma unroll
  for (int cc=0; cc<8; cc++){
    short8 Bf = *(const short8*)(bfp + cc*32);
    short8 Bi = *(const short8*)(bp0 + cc*32);
    short8 Bo = *(const short8*)(bp1 + cc*32);
    short8 Bu = *(const short8*)(bp2 + cc*32);
    #pragma unroll
    for (int r=0;r<4;r++){
      short8 a = *(const short8*)&Ch[cc][(16*r + l15)*40 + quad*8];
      af[r] = __builtin_amdgcn_mfma_f32_16x16x32_bf16(a, Bf, af[r], 0,0,0);
      ai[r] = __builtin_amdgcn_mfma_f32_16x16x32_bf16(a, Bi, ai[r], 0,0,0);
      ao[r] = __builtin_amdgcn_mfma_f32_16x16x32_bf16(a, Bo, ao[r], 0,0,0);
      au[r] = __builtin_amdgcn_mfma_f32_16x16x32_bf16(a, Bu, au[r], 0,0,0);
    }
  }

  float ufb = Ufb[col];
  float bI = biou[col], bO = biou[256+col], bU = biou[512+col];
  #pragma unroll
  for (int r=0;r<4;r++){
    int m = m0 + 4*r + quad;
    int mm = m < M ? m : M-1;
    int tree = mm >> shift, loc = base + (mm & mask);
    size_t ch0 = ((size_t)tree*NPT + 4*loc + 1)*256 + col;
    float cs = 0.f;
    #pragma unroll
    for (int reg=0;reg<4;reg++)
      cs += sigf(af[r][reg] + ufb) * bf2f(c[ch0 + (size_t)reg*256]);
    float iv = ai[r][0]+ai[r][1]+ai[r][2]+ai[r][3] + bI;
    float ov = ao[r][0]+ao[r][1]+ao[r][2]+ao[r][3] + bO;
    float uv = au[r][0]+au[r][1]+au[r][2]+au[r][3] + bU;
    float cn = sigf(iv)*tanh_fast(uv) + cs;
    float hn = sigf(ov)*tanh_fast(cn);
    if (m < M){
      size_t off = ((size_t)tree*NPT + loc)*256 + col;
      h[off] = f2bf(hn);
      c[off] = f2bf(cn);
    }
  }
}

// ---------- readout partials: vectorized (ushort4/lane, 4 row-groups) -------
__global__ __launch_bounds__(256) void readout_k(
    const ushort* __restrict__ h1, const ushort* __restrict__ h2,
    float* __restrict__ mp1, float* __restrict__ mp2){
  __shared__ float red[4][256];
  int br = blockIdx.z, part = blockIdx.y, tree = blockIdx.x;
  const ushort* h = br ? h2 : h1;
  float* mp = br ? mp2 : mp1;
  int t = threadIdx.x;
  int lane = t & 63, rg = t >> 6;
  int start = part*85;
  int cnt = (part==3) ? 86 : 85;
  const ushort* base = h + ((size_t)tree*NPT + start)*256 + lane*4;
  float s0=0.f,s1=0.f,s2=0.f,s3=0.f;
  for (int i=rg; i<cnt; i+=4){
    ushort4 v = *(const ushort4*)(base + (size_t)i*256);
    s0 += bf2f(v.x); s1 += bf2f(v.y); s2 += bf2f(v.z); s3 += bf2f(v.w);
  }
  *(float4*)&red[rg][lane*4] = make_float4(s0,s1,s2,s3);
  __syncthreads();
  float tot = red[0][t]+red[1][t]+red[2][t]+red[3][t];
  mp[((size_t)tree*4 + part)*256 + t] = tot;
}

// ---------- final: mean->relu->concat@Wf->leaky_relu->softmax ---------------
__global__ __launch_bounds__(64) void final_k(const float* __restrict__ mp1,
    const float* __restrict__ mp2, const float* __restrict__ Wf,
    const float* __restrict__ bf, float* __restrict__ out){
  int tree = blockIdx.x; int t = threadIdx.x;
  float p0=0.f, p1=0.f;
  for (int k=t;k<512;k+=64){
    const float* mp = (k<256) ? mp1 : mp2;
    int kk = k & 255;
    size_t b0 = ((size_t)tree*4)*256 + kk;
    float s = mp[b0] + mp[b0+256] + mp[b0+512] + mp[b0+768];
    float x = fmaxf(s*(1.0f/341.0f), 0.f);
    p0 += x*Wf[k*2+0]; p1 += x*Wf[k*2+1];
  }
  #pragma unroll
  for (int off=32; off>0; off>>=1){
    p0 += __shfl_down(p0, off);
    p1 += __shfl_down(p1, off);
  }
  if (t==0){
    float l0 = p0+bf[0], l1 = p1+bf[1];
    l0 = (l0>0.f)?l0:0.01f*l0;
    l1 = (l1>0.f)?l1:0.01f*l1;
    float mx = fmaxf(l0,l1);
    float e0 = __expf(l0-mx), e1 = __expf(l1-mx);
    float inv = 1.0f/(e0+e1);
    out[tree*2+0] = e0*inv; out[tree*2+1] = e1*inv;
  }
}

extern "C" void kernel_launch(void* const* d_in, const int* in_sizes, int n_in,
                              void* d_out, int out_size, void* d_ws, size_t ws_size,
                              hipStream_t stream) {
  const int*   feat1 = (const int*)  d_in[0];
  const int*   feat2 = (const int*)  d_in[1];
  const float* emb1  = (const float*)d_in[2];
  const float* emb2  = (const float*)d_in[3];
  const float* Wiou1 = (const float*)d_in[4];
  const float* Wiou2 = (const float*)d_in[5];
  const float* Uiou1 = (const float*)d_in[6];
  const float* Uiou2 = (const float*)d_in[7];
  const float* UfW1  = (const float*)d_in[8];
  const float* Ufb1  = (const float*)d_in[9];
  const float* UfW2  = (const float*)d_in[10];
  const float* Ufb2  = (const float*)d_in[11];
  const float* biou1 = (const float*)d_in[12];
  const float* biou2 = (const float*)d_in[13];
  const float* Wf    = (const float*)d_in[14];
  const float* bfv   = (const float*)d_in[15];
  float* out = (float*)d_out;

  char* ws = (char*)d_ws;
  ushort* h1  = (ushort*)ws;  ws += (size_t)NN*256*2;   // 26.2 MB
  ushort* h2  = (ushort*)ws;  ws += (size_t)NN*256*2;
  ushort* c1  = (ushort*)ws;  ws += (size_t)NN*256*2;
  ushort* c2  = (ushort*)ws;  ws += (size_t)NN*256*2;
  ushort* E1  = (ushort*)ws;  ws += (size_t)VOCAB*256*2; // 5.12 MB
  ushort* E2  = (ushort*)ws;  ws += (size_t)VOCAB*256*2;
  ushort* Wt1 = (ushort*)ws;  ws += 768*256*2;
  ushort* Ut1 = (ushort*)ws;  ws += 768*256*2;
  ushort* Ft1 = (ushort*)ws;  ws += 256*256*2;
  ushort* Wt2 = (ushort*)ws;  ws += 768*256*2;
  ushort* Ut2 = (ushort*)ws;  ws += 768*256*2;
  ushort* Ft2 = (ushort*)ws;  ws += 256*256*2;
  float*  mp1 = (float*)ws;   ws += (size_t)NT*4*256*4;
  float*  mp2 = (float*)ws;   ws += (size_t)NT*4*256*4;

  prep_k<<<dim3(6152), 256, 0, stream>>>(emb1, emb2, E1, E2,
                                         Wiou1, Uiou1, UfW1, Wiou2, Uiou2, UfW2,
                                         Wt1, Ut1, Ft1, Wt2, Ut2, Ft2);
  leaf_gemm<<<dim3(NL/32, 2), 512, 0, stream>>>(feat1, feat2, E1, E2,
                                                Wt1, biou1, Wt2, biou2,
                                                h1, c1, h2, c2);

  const int lvlM[4]     = {9600, 2400, 600, 150};
  const int lvlShift[4] = {6, 4, 2, 0};
  const int lvlBase[4]  = {21, 5, 1, 0};
  for (int l=0;l<4;l++){
    int gx = (lvlM[l] + 15)/16;
    level_k<<<dim3(gx, 2, 2), 512, 0, stream>>>(Ut1, Ft1, Ufb1, biou1,
                                                Ut2, Ft2, Ufb2, biou2,
                                                h1, c1, h2, c2,
                                                lvlM[l], lvlShift[l], lvlBase[l]);
  }
  readout_k<<<dim3(NT, 4, 2), 256, 0, stream>>>(h1, h2, mp1, mp2);
  final_k<<<NT, 64, 0, stream>>>(mp1, mp2, Wf, bfv, out);
}

// Round 4
// 367.450 us; speedup vs baseline: 1.2094x; 1.0981x over previous
//
#include <hip/hip_runtime.h>

#define NT 150      // trees
#define NPT 341     // nodes per tree
#define LEAF0 85    // first leaf local index
#define NL (NT*256) // 38400 leaves
#define NN (NT*NPT) // 51150 nodes
#define VOCAB 10000

typedef __attribute__((ext_vector_type(8))) short short8;
typedef __attribute__((ext_vector_type(4))) float floatx4;

__device__ __forceinline__ float sigf(float x){
  return __builtin_amdgcn_rcpf(1.0f + __expf(-x));
}
__device__ __forceinline__ float tanh_fast(float x){
  float e = __expf(2.0f*x);
  return 1.0f - 2.0f*__builtin_amdgcn_rcpf(e + 1.0f);
}
__device__ __forceinline__ float bf2f(ushort u){ union{unsigned i; float f;} v; v.i = ((unsigned)u)<<16; return v.f; }
__device__ __forceinline__ ushort f2bf(float x){ union{float f; unsigned i;} v; v.f = x; return (ushort)((v.i + 0x7fff + ((v.i>>16)&1))>>16); }

// ---------- prep: weight transpose+convert AND embedding-table convert ------
__global__ __launch_bounds__(256) void prep_k(
    const float* __restrict__ e1, const float* __restrict__ e2,
    ushort* __restrict__ E1, ushort* __restrict__ E2,
    const float* __restrict__ W1, const float* __restrict__ U1, const float* __restrict__ F1,
    const float* __restrict__ W2, const float* __restrict__ U2, const float* __restrict__ F2,
    ushort* Wt1, ushort* Ut1, ushort* Ft1, ushort* Wt2, ushort* Ut2, ushort* Ft2){
  __shared__ float T[32][33];
  int bid = blockIdx.x;
  if (bid < 5000){
    const float* s = (bid >= 2500) ? e2 : e1;
    ushort* d = (bid >= 2500) ? E2 : E1;
    size_t i = ((size_t)(bid % 2500)*256 + threadIdx.x)*4;
    float4 v = *(const float4*)&s[i];
    d[i+0]=f2bf(v.x); d[i+1]=f2bf(v.y); d[i+2]=f2bf(v.z); d[i+3]=f2bf(v.w);
    return;
  }
  int w = bid - 5000;            // [0, 1152)
  int z = w / 192, rem = w % 192;
  int bx = rem % 24, by = rem / 24;
  const float* src; ushort* dst; int N;
  switch (z){
    case 0: src=W1; dst=Wt1; N=768; break;
    case 1: src=U1; dst=Ut1; N=768; break;
    case 2: src=F1; dst=Ft1; N=256; break;
    case 3: src=W2; dst=Wt2; N=768; break;
    case 4: src=U2; dst=Ut2; N=768; break;
    default: src=F2; dst=Ft2; N=256; break;
  }
  int n0 = bx*32; if (n0 >= N) return;
  int k0 = by*32;
  int nl = threadIdx.x & 31, kb = threadIdx.x >> 5;
  #pragma unroll
  for (int i=0;i<4;i++){ int kk = kb*4+i; T[kk][nl] = src[(size_t)(k0+kk)*N + n0 + nl]; }
  __syncthreads();
  #pragma unroll
  for (int i=0;i<4;i++){ int nn = kb*4+i; dst[(size_t)(n0+nn)*256 + k0 + nl] = f2bf(T[nl][nn]); }
}

// ---------- fused leaf + level-1: embed -> W_iou GEMM -> leaf LSTM ->
//            U GEMM over the same 64 children -> lvl1 LSTM, one block --------
// 64 leaves (one tree, 64-aligned) = children of 16 consecutive lvl1 nodes.
// Lane-local identity: epi1 thread (wav,quad,l15) produces c for leaf rows
// 16r+4*quad+reg at col wav*16+l15; epi2 node m_local=4r+quad needs f*c over
// children rows 16r+4*quad+{0..3} at the same col -> c stays in registers.
__global__ __launch_bounds__(1024, 4) void leaf_lvl1_k(
    const int* __restrict__ f1, const int* __restrict__ f2,
    const ushort* __restrict__ E1, const ushort* __restrict__ E2,
    const ushort* __restrict__ Wt1, const ushort* __restrict__ Ut1,
    const ushort* __restrict__ Ft1, const float* __restrict__ b1,
    const float* __restrict__ Ufb1,
    const ushort* __restrict__ Wt2, const ushort* __restrict__ Ut2,
    const ushort* __restrict__ Ft2, const float* __restrict__ b2,
    const float* __restrict__ Ufb2,
    ushort* __restrict__ h1, ushort* __restrict__ c1,
    ushort* __restrict__ h2, ushort* __restrict__ c2){
  __shared__ __attribute__((aligned(16))) ushort As[8][64*40];  // 40 KB, reused
  int br = blockIdx.y;
  const int* feat = br ? f2 : f1;
  const ushort* E = br ? E2 : E1;
  const ushort* Wt = br ? Wt2 : Wt1;
  const ushort* Ut = br ? Ut2 : Ut1;
  const ushort* Ft = br ? Ft2 : Ft1;
  const float* biou = br ? b2 : b1;
  const float* Ufb = br ? Ufb2 : Ufb1;
  ushort* h = br ? h2 : h1;
  ushort* c = br ? c2 : c1;
  int tid = threadIdx.x;
  int lane = tid & 63, wav = tid >> 6, quad = lane >> 4, l15 = lane & 15;
  int rowbase = blockIdx.x*64;
  int tree = rowbase >> 8, lbase = rowbase & 255;
  size_t tb = (size_t)tree*NPT;

  { // fused embed: mean of 8 subtoken rows -> bf16 -> LDS A-tile
    int row = tid >> 4, seg = tid & 15;
    size_t node = tb + LEAF0 + lbase + row;
    const int* f = feat + node*8;
    int4 fA = *(const int4*)f;
    int4 fB = *(const int4*)(f+4);
    int idx[8] = {fA.x, fA.y, fA.z, fA.w, fB.x, fB.y, fB.z, fB.w};
    float s[16];
    #pragma unroll
    for (int q=0;q<16;q++) s[q]=0.f;
    #pragma unroll
    for (int half=0; half<2; half++){
      short8 va[4], vb[4];
      #pragma unroll
      for (int j=0;j<4;j++){
        const ushort* rowp = E + (size_t)idx[half*4+j]*256 + seg*16;
        va[j] = *(const short8*)rowp;
        vb[j] = *(const short8*)(rowp+8);
      }
      #pragma unroll
      for (int j=0;j<4;j++){
        #pragma unroll
        for (int q=0;q<8;q++){ s[q]+=bf2f((ushort)va[j][q]); s[8+q]+=bf2f((ushort)vb[j][q]); }
      }
    }
    short8 o1, o2;
    #pragma unroll
    for (int q=0;q<8;q++){ o1[q]=(short)f2bf(s[q]*0.125f); o2[q]=(short)f2bf(s[8+q]*0.125f); }
    int cch = seg >> 1, off = (seg & 1)*16;
    *(short8*)&As[cch][row*40 + off]     = o1;
    *(short8*)&As[cch][row*40 + off + 8] = o2;
  }
  __syncthreads();

  // ---- GEMM1: iou0 = embeds @ W_iou (64 x 768) ----
  floatx4 acc[3][4];
  #pragma unroll
  for (int g=0;g<3;g++)
    #pragma unroll
    for (int r=0;r<4;r++) acc[g][r] = (floatx4){0.f,0.f,0.f,0.f};

  int hc = wav*16 + l15;
  const ushort* bp0 = Wt + (size_t)(0*256 + hc)*256 + quad*8;
  const ushort* bp1 = Wt + (size_t)(256 + hc)*256 + quad*8;
  const ushort* bp2 = Wt + (size_t)(512 + hc)*256 + quad*8;

  #pragma unroll
  for (int cch=0; cch<8; cch++){
    short8 b0 = *(const short8*)(bp0 + cch*32);
    short8 b1 = *(const short8*)(bp1 + cch*32);
    short8 b2 = *(const short8*)(bp2 + cch*32);
    #pragma unroll
    for (int r=0;r<4;r++){
      short8 a = *(const short8*)&As[cch][(16*r + l15)*40 + quad*8];
      acc[0][r] = __builtin_amdgcn_mfma_f32_16x16x32_bf16(a, b0, acc[0][r], 0,0,0);
      acc[1][r] = __builtin_amdgcn_mfma_f32_16x16x32_bf16(a, b1, acc[1][r], 0,0,0);
      acc[2][r] = __builtin_amdgcn_mfma_f32_16x16x32_bf16(a, b2, acc[2][r], 0,0,0);
    }
  }
  __syncthreads();   // all As reads done; buffer reused for h tile

  // ---- epi1: leaf LSTM; h -> global + LDS(A2), c -> registers ----
  float bi = biou[hc], bo = biou[256+hc], bu = biou[512+hc];
  float cv[16];
  #pragma unroll
  for (int r=0;r<4;r++){
    #pragma unroll
    for (int reg=0;reg<4;reg++){
      int row = 16*r + quad*4 + reg;
      float iv = acc[0][r][reg] + bi;
      float ov = acc[1][r][reg] + bo;
      float uv = acc[2][r][reg] + bu;
      float cc = sigf(iv)*tanh_fast(uv);
      float hh = sigf(ov)*tanh_fast(cc);
      cv[4*r+reg] = cc;
      ushort hb = f2bf(hh);
      h[(tb + LEAF0 + lbase + row)*256 + hc] = hb;
      As[hc>>5][row*40 + (hc & 31)] = hb;
    }
  }
  __syncthreads();

  // ---- GEMM2: {f,i,o,u} = h_children @ {Uf, U_iou}, col = hc ----
  const ushort* bfp = Ft + (size_t)hc*256 + quad*8;
  const ushort* up0 = Ut + (size_t)(0*256 + hc)*256 + quad*8;
  const ushort* up1 = Ut + (size_t)(256 + hc)*256 + quad*8;
  const ushort* up2 = Ut + (size_t)(512 + hc)*256 + quad*8;

  floatx4 af[4], ai[4], ao[4], au[4];
  #pragma unroll
  for (int r=0;r<4;r++){
    af[r] = (floatx4){0.f,0.f,0.f,0.f}; ai[r] = (floatx4){0.f,0.f,0.f,0.f};
    ao[r] = (floatx4){0.f,0.f,0.f,0.f}; au[r] = (floatx4){0.f,0.f,0.f,0.f};
  }
  #pragma unroll
  for (int cch=0; cch<8; cch++){
    short8 Bf = *(const short8*)(bfp + cch*32);
    short8 Bi = *(const short8*)(up0 + cch*32);
    short8 Bo = *(const short8*)(up1 + cch*32);
    short8 Bu = *(const short8*)(up2 + cch*32);
    #pragma unroll
    for (int r=0;r<4;r++){
      short8 a = *(const short8*)&As[cch][(16*r + l15)*40 + quad*8];
      af[r] = __builtin_amdgcn_mfma_f32_16x16x32_bf16(a, Bf, af[r], 0,0,0);
      ai[r] = __builtin_amdgcn_mfma_f32_16x16x32_bf16(a, Bi, ai[r], 0,0,0);
      ao[r] = __builtin_amdgcn_mfma_f32_16x16x32_bf16(a, Bo, ao[r], 0,0,0);
      au[r] = __builtin_amdgcn_mfma_f32_16x16x32_bf16(a, Bu, au[r], 0,0,0);
    }
  }

  // ---- epi2: 16 lvl1 nodes; children c are lane-local (cv) ----
  int nodebase = 21 + (lbase >> 2);
  float ufb = Ufb[hc];
  float bI = biou[hc], bO = biou[256+hc], bU = biou[512+hc];
  #pragma unroll
  for (int r=0;r<4;r++){
    int m_local = 4*r + quad;
    float cs = 0.f;
    #pragma unroll
    for (int reg=0;reg<4;reg++)
      cs += sigf(af[r][reg] + ufb) * cv[4*r+reg];
    float iv = ai[r][0]+ai[r][1]+ai[r][2]+ai[r][3] + bI;
    float ov = ao[r][0]+ao[r][1]+ao[r][2]+ao[r][3] + bO;
    float uv = au[r][0]+au[r][1]+au[r][2]+au[r][3] + bU;
    float cn = sigf(iv)*tanh_fast(uv) + cs;
    float hn = sigf(ov)*tanh_fast(cn);
    size_t off = (tb + nodebase + m_local)*256 + hc;
    h[off] = f2bf(hn);
    c[off] = f2bf(cn);
  }
}

// ---------- internal level, 512 threads: 16 nodes x 128 cols per block ------
__global__ __launch_bounds__(512) void level_k(
    const ushort* __restrict__ Ut1, const ushort* __restrict__ Ft1,
    const float* __restrict__ Ufb1, const float* __restrict__ bi1,
    const ushort* __restrict__ Ut2, const ushort* __restrict__ Ft2,
    const float* __restrict__ Ufb2, const float* __restrict__ bi2,
    ushort* __restrict__ h1, ushort* __restrict__ c1,
    ushort* __restrict__ h2, ushort* __restrict__ c2,
    int M, int shift, int base){
  __shared__ __attribute__((aligned(16))) ushort Ch[8][64*40];  // 40 KB
  int br = blockIdx.z;
  const ushort* Ut = br ? Ut2 : Ut1;
  const ushort* Ft = br ? Ft2 : Ft1;
  const float* Ufb = br ? Ufb2 : Ufb1;
  const float* biou = br ? bi2 : bi1;
  ushort* h = br ? h2 : h1;
  ushort* c = br ? c2 : c1;
  int tid = threadIdx.x;
  int lane = tid & 63, wav = tid >> 6, quad = lane >> 4, l15 = lane & 15;
  int m0 = blockIdx.x*16;
  int mask = (1<<shift)-1;

  { // stage 64 children rows x 256 k (8 threads/row, 64 B each)
    int cl = tid >> 3, s8 = tid & 7;
    int sm = m0 + (cl >> 2); if (sm > M-1) sm = M-1;
    int stree = sm >> shift, sloc = base + (sm & mask);
    const ushort* sgp = h + ((size_t)stree*NPT + 4*sloc + 1 + (cl & 3))*256 + s8*32;
    short8 v0 = *(const short8*)(sgp);
    short8 v1 = *(const short8*)(sgp+8);
    short8 v2 = *(const short8*)(sgp+16);
    short8 v3 = *(const short8*)(sgp+24);
    *(short8*)&Ch[s8][cl*40 + 0]  = v0;
    *(short8*)&Ch[s8][cl*40 + 8]  = v1;
    *(short8*)&Ch[s8][cl*40 + 16] = v2;
    *(short8*)&Ch[s8][cl*40 + 24] = v3;
  }
  __syncthreads();

  int col = blockIdx.y*128 + wav*16 + l15;
  const ushort* bfp = Ft + (size_t)col*256 + quad*8;
  const ushort* bp0 = Ut + (size_t)(0*256 + col)*256 + quad*8;
  const ushort* bp1 = Ut + (size_t)(256 + col)*256 + quad*8;
  const ushort* bp2 = Ut + (size_t)(512 + col)*256 + quad*8;

  floatx4 af[4], ai[4], ao[4], au[4];
  #pragma unroll
  for (int r=0;r<4;r++){
    af[r] = (floatx4){0.f,0.f,0.f,0.f}; ai[r] = (floatx4){0.f,0.f,0.f,0.f};
    ao[r] = (floatx4){0.f,0.f,0.f,0.f}; au[r] = (floatx4){0.f,0.f,0.f,0.f};
  }

  #pragma unroll
  for (int cc=0; cc<8; cc++){
    short8 Bf = *(const short8*)(bfp + cc*32);
    short8 Bi = *(const short8*)(bp0 + cc*32);
    short8 Bo = *(const short8*)(bp1 + cc*32);
    short8 Bu = *(const short8*)(bp2 + cc*32);
    #pragma unroll
    for (int r=0;r<4;r++){
      short8 a = *(const short8*)&Ch[cc][(16*r + l15)*40 + quad*8];
      af[r] = __builtin_amdgcn_mfma_f32_16x16x32_bf16(a, Bf, af[r], 0,0,0);
      ai[r] = __builtin_amdgcn_mfma_f32_16x16x32_bf16(a, Bi, ai[r], 0,0,0);
      ao[r] = __builtin_amdgcn_mfma_f32_16x16x32_bf16(a, Bo, ao[r], 0,0,0);
      au[r] = __builtin_amdgcn_mfma_f32_16x16x32_bf16(a, Bu, au[r], 0,0,0);
    }
  }

  float ufb = Ufb[col];
  float bI = biou[col], bO = biou[256+col], bU = biou[512+col];
  #pragma unroll
  for (int r=0;r<4;r++){
    int m = m0 + 4*r + quad;
    int mm = m < M ? m : M-1;
    int tree = mm >> shift, loc = base + (mm & mask);
    size_t ch0 = ((size_t)tree*NPT + 4*loc + 1)*256 + col;
    float cs = 0.f;
    #pragma unroll
    for (int reg=0;reg<4;reg++)
      cs += sigf(af[r][reg] + ufb) * bf2f(c[ch0 + (size_t)reg*256]);
    float iv = ai[r][0]+ai[r][1]+ai[r][2]+ai[r][3] + bI;
    float ov = ao[r][0]+ao[r][1]+ao[r][2]+ao[r][3] + bO;
    float uv = au[r][0]+au[r][1]+au[r][2]+au[r][3] + bU;
    float cn = sigf(iv)*tanh_fast(uv) + cs;
    float hn = sigf(ov)*tanh_fast(cn);
    if (m < M){
      size_t off = ((size_t)tree*NPT + loc)*256 + col;
      h[off] = f2bf(hn);
      c[off] = f2bf(cn);
    }
  }
}

// ---------- readout partials: vectorized (ushort4/lane, 4 row-groups) -------
__global__ __launch_bounds__(256) void readout_k(
    const ushort* __restrict__ h1, const ushort* __restrict__ h2,
    float* __restrict__ mp1, float* __restrict__ mp2){
  __shared__ float red[4][256];
  int br = blockIdx.z, part = blockIdx.y, tree = blockIdx.x;
  const ushort* h = br ? h2 : h1;
  float* mp = br ? mp2 : mp1;
  int t = threadIdx.x;
  int lane = t & 63, rg = t >> 6;
  int start = part*85;
  int cnt = (part==3) ? 86 : 85;
  const ushort* base = h + ((size_t)tree*NPT + start)*256 + lane*4;
  float s0=0.f,s1=0.f,s2=0.f,s3=0.f;
  for (int i=rg; i<cnt; i+=4){
    ushort4 v = *(const ushort4*)(base + (size_t)i*256);
    s0 += bf2f(v.x); s1 += bf2f(v.y); s2 += bf2f(v.z); s3 += bf2f(v.w);
  }
  *(float4*)&red[rg][lane*4] = make_float4(s0,s1,s2,s3);
  __syncthreads();
  float tot = red[0][t]+red[1][t]+red[2][t]+red[3][t];
  mp[((size_t)tree*4 + part)*256 + t] = tot;
}

// ---------- final: mean->relu->concat@Wf->leaky_relu->softmax ---------------
__global__ __launch_bounds__(64) void final_k(const float* __restrict__ mp1,
    const float* __restrict__ mp2, const float* __restrict__ Wf,
    const float* __restrict__ bf, float* __restrict__ out){
  int tree = blockIdx.x; int t = threadIdx.x;
  float p0=0.f, p1=0.f;
  for (int k=t;k<512;k+=64){
    const float* mp = (k<256) ? mp1 : mp2;
    int kk = k & 255;
    size_t b0 = ((size_t)tree*4)*256 + kk;
    float s = mp[b0] + mp[b0+256] + mp[b0+512] + mp[b0+768];
    float x = fmaxf(s*(1.0f/341.0f), 0.f);
    p0 += x*Wf[k*2+0]; p1 += x*Wf[k*2+1];
  }
  #pragma unroll
  for (int off=32; off>0; off>>=1){
    p0 += __shfl_down(p0, off);
    p1 += __shfl_down(p1, off);
  }
  if (t==0){
    float l0 = p0+bf[0], l1 = p1+bf[1];
    l0 = (l0>0.f)?l0:0.01f*l0;
    l1 = (l1>0.f)?l1:0.01f*l1;
    float mx = fmaxf(l0,l1);
    float e0 = __expf(l0-mx), e1 = __expf(l1-mx);
    float inv = 1.0f/(e0+e1);
    out[tree*2+0] = e0*inv; out[tree*2+1] = e1*inv;
  }
}

extern "C" void kernel_launch(void* const* d_in, const int* in_sizes, int n_in,
                              void* d_out, int out_size, void* d_ws, size_t ws_size,
                              hipStream_t stream) {
  const int*   feat1 = (const int*)  d_in[0];
  const int*   feat2 = (const int*)  d_in[1];
  const float* emb1  = (const float*)d_in[2];
  const float* emb2  = (const float*)d_in[3];
  const float* Wiou1 = (const float*)d_in[4];
  const float* Wiou2 = (const float*)d_in[5];
  const float* Uiou1 = (const float*)d_in[6];
  const float* Uiou2 = (const float*)d_in[7];
  const float* UfW1  = (const float*)d_in[8];
  const float* Ufb1  = (const float*)d_in[9];
  const float* UfW2  = (const float*)d_in[10];
  const float* Ufb2  = (const float*)d_in[11];
  const float* biou1 = (const float*)d_in[12];
  const float* biou2 = (const float*)d_in[13];
  const float* Wf    = (const float*)d_in[14];
  const float* bfv   = (const float*)d_in[15];
  float* out = (float*)d_out;

  char* ws = (char*)d_ws;
  ushort* h1  = (ushort*)ws;  ws += (size_t)NN*256*2;   // 26.2 MB
  ushort* h2  = (ushort*)ws;  ws += (size_t)NN*256*2;
  ushort* c1  = (ushort*)ws;  ws += (size_t)NN*256*2;
  ushort* c2  = (ushort*)ws;  ws += (size_t)NN*256*2;
  ushort* E1  = (ushort*)ws;  ws += (size_t)VOCAB*256*2; // 5.12 MB
  ushort* E2  = (ushort*)ws;  ws += (size_t)VOCAB*256*2;
  ushort* Wt1 = (ushort*)ws;  ws += 768*256*2;
  ushort* Ut1 = (ushort*)ws;  ws += 768*256*2;
  ushort* Ft1 = (ushort*)ws;  ws += 256*256*2;
  ushort* Wt2 = (ushort*)ws;  ws += 768*256*2;
  ushort* Ut2 = (ushort*)ws;  ws += 768*256*2;
  ushort* Ft2 = (ushort*)ws;  ws += 256*256*2;
  float*  mp1 = (float*)ws;   ws += (size_t)NT*4*256*4;
  float*  mp2 = (float*)ws;   ws += (size_t)NT*4*256*4;

  prep_k<<<dim3(6152), 256, 0, stream>>>(emb1, emb2, E1, E2,
                                         Wiou1, Uiou1, UfW1, Wiou2, Uiou2, UfW2,
                                         Wt1, Ut1, Ft1, Wt2, Ut2, Ft2);
  leaf_lvl1_k<<<dim3(NL/64, 2), 1024, 0, stream>>>(feat1, feat2, E1, E2,
                                                   Wt1, Ut1, Ft1, biou1, Ufb1,
                                                   Wt2, Ut2, Ft2, biou2, Ufb2,
                                                   h1, c1, h2, c2);

  const int lvlM[3]     = {2400, 600, 150};
  const int lvlShift[3] = {4, 2, 0};
  const int lvlBase[3]  = {5, 1, 0};
  for (int l=0;l<3;l++){
    int gx = (lvlM[l] + 15)/16;
    level_k<<<dim3(gx, 2, 2), 512, 0, stream>>>(Ut1, Ft1, Ufb1, biou1,
                                                Ut2, Ft2, Ufb2, biou2,
                                                h1, c1, h2, c2,
                                                lvlM[l], lvlShift[l], lvlBase[l]);
  }
  readout_k<<<dim3(NT, 4, 2), 256, 0, stream>>>(h1, h2, mp1, mp2);
  final_k<<<NT, 64, 0, stream>>>(mp1, mp2, Wf, bfv, out);
}